// Round 15
// baseline (390.860 us; speedup 1.0000x reference)
//
#include <hip/hip_runtime.h>
#include <math.h>

// ---------------------------------------------------------------------------
// GAT pipeline (R15 = R14 + dispatch trimming):
//   prep (wsplit + degree count) -> scan1 -> scan3(self-carry) -> scatter
//   L0: fp32-A split-bf16 MFMA GEMM (3 mfma, BM=64) -> xl fp8 + stats
//   L1: bf16-A GEMM BM=128 (2 mfma);  L2: bf16-A GEMM BM=64
//   agg4 x2: single-pass exp gather (fp8, batch-8), bf16 h out
//   agg1+pool fused (block-reduce -> 128 atomicAdds); mlp
// R14: 323.5us. Launch gaps (~25us/14 dispatches) + pool/h2 round-trip are
//   now top-3 items. R15: -2 dispatches (pool fused into agg1, scan2 folded
//   into scan3's local carry reduce), h2 array eliminated (20MB less traffic).
// ---------------------------------------------------------------------------

typedef float f32x4 __attribute__((ext_vector_type(4)));
typedef float f32x2 __attribute__((ext_vector_type(2)));
typedef short s16x8 __attribute__((ext_vector_type(8)));
typedef short s16x4 __attribute__((ext_vector_type(4)));

__device__ inline ushort f2bf(float f) {
  unsigned u = __float_as_uint(f);
  u += 0x7FFF + ((u >> 16) & 1);          // round-to-nearest-even
  return (ushort)(u >> 16);
}
__device__ inline float bf2f(ushort h) { return __uint_as_float((unsigned)h << 16); }
__device__ inline unsigned char f2fp8(float f) {
  int p = __builtin_amdgcn_cvt_pk_fp8_f32(f, f, 0, false);
  return (unsigned char)(p & 0xFF);
}

// ------- prep: weight transpose/split (idx<98304) + degree count (rest) ----
__global__ void prep_kernel(
    const float* __restrict__ W0, const float* __restrict__ W1,
    const float* __restrict__ W2, ushort* __restrict__ w0h, ushort* __restrict__ w0l,
    ushort* __restrict__ w1h, ushort* __restrict__ w1l, ushort* __restrict__ w2h,
    ushort* __restrict__ w2l, const int* __restrict__ ei, int* __restrict__ counts,
    int E, int n) {
  int idx = blockIdx.x * 256 + threadIdx.x;
  if (idx >= 98304) {
    int t = idx - 98304;
    if (t < E)          atomicAdd(&counts[ei[E + t]], 1);
    else if (t < E + n) atomicAdd(&counts[t - E], 1);
    return;
  }
  const float* W; ushort *th, *tl; int K, N;
  if (idx < 16384)      { W = W0; th = w0h; tl = w0l; K = 128; N = 512; }
  else if (idx < 81920) { idx -= 16384; W = W1; th = w1h; tl = w1l; K = 512; N = 512; }
  else                  { idx -= 81920; W = W2; th = w2h; tl = w2l; K = 512; N = 128; }
  int nn = idx % N;
  int k4 = (idx / N) << 2;
  s16x4 hv, lv;
#pragma unroll
  for (int r = 0; r < 4; ++r) {
    float w = W[(size_t)(k4 + r) * N + nn];
    ushort h = f2bf(w);
    hv[r] = (short)h;
    lv[r] = (short)f2bf(w - bf2f(h));
  }
  *(s16x4*)&th[(size_t)nn * K + k4] = hv;
  *(s16x4*)&tl[(size_t)nn * K + k4] = lv;
}

__global__ void scan1_kernel(const int* __restrict__ counts, int* __restrict__ partials,
                             int n) {
  __shared__ int sd[4];
  int i = blockIdx.x * 256 + threadIdx.x;
  int v = (i < n) ? counts[i] : 0;
  for (int m = 32; m; m >>= 1) v += __shfl_xor(v, m);
  if ((threadIdx.x & 63) == 0) sd[threadIdx.x >> 6] = v;
  __syncthreads();
  if (threadIdx.x == 0) partials[blockIdx.x] = sd[0] + sd[1] + sd[2] + sd[3];
}

// scan3 with self-computed carry (folds old scan2): partials are RAW per-block
// sums; each block reduces partials[0..blockIdx.x) itself (nb <= 256).
__global__ void scan3_kernel(const int* __restrict__ counts, const int* __restrict__ partials,
                             int* __restrict__ offsets, int n) {
  __shared__ int sd[256];
  __shared__ int cw[4];
  __shared__ int carry_sh;
  int t = threadIdx.x;
  int pv = (t < blockIdx.x) ? partials[t] : 0;
  for (int m = 32; m; m >>= 1) pv += __shfl_xor(pv, m);
  if ((t & 63) == 0) cw[t >> 6] = pv;
  __syncthreads();
  if (t == 0) carry_sh = cw[0] + cw[1] + cw[2] + cw[3];
  int i = blockIdx.x * 256 + t;
  int v = (i < n) ? counts[i] : 0;
  sd[t] = v;
  __syncthreads();
  for (int off = 1; off < 256; off <<= 1) {
    int u = (t >= off) ? sd[t - off] : 0;
    __syncthreads();
    sd[t] += u;
    __syncthreads();
  }
  int carry = carry_sh;
  if (i < n) {
    offsets[i] = carry + sd[t] - v;
    if (i == n - 1) offsets[n] = carry + sd[t];
  }
}

__global__ void scatter_kernel(const int* __restrict__ ei, const int* __restrict__ offsets,
                               int* __restrict__ cursor, int* __restrict__ srcs,
                               int E, int n) {
  int t = blockIdx.x * blockDim.x + threadIdx.x;
  int s, d;
  if (t < E)          { s = ei[t]; d = ei[E + t]; }
  else if (t < E + n) { s = t - E; d = s; }
  else return;
  int pos = offsets[d] + atomicAdd(&cursor[d], 1);
  srcs[pos] = s;
}

// ---------------- shared GEMM epilogue (fp8 store + fused stats) ----------
template <int NC>
__device__ inline void gemm_epilogue(
    f32x4 (&acc)[2][4], unsigned char* __restrict__ Cb, const float* __restrict__ a_s,
    const float* __restrict__ a_d, float* __restrict__ asn, float* __restrict__ adn,
    float (*st_sh)[64][2], int M, int row0, int col0, int hidx,
    int tid, int lane, int wid, int wm, int wn, int fr) {
  constexpr int N = NC * 128;
  float asv[4], adv[4];
#pragma unroll
  for (int j = 0; j < 4; ++j) {
    asv[j] = a_s[hidx * 128 + wn + j * 16 + fr];
    adv[j] = a_d[hidx * 128 + wn + j * 16 + fr];
  }
  int rb = row0 + wm + ((lane >> 4) << 2);
  int cb = col0 + wn + fr;
#pragma unroll
  for (int i = 0; i < 2; ++i)
#pragma unroll
    for (int r = 0; r < 4; ++r) {
      int row = rb + i * 16 + r;
      float sp = 0.f, dp = 0.f;
#pragma unroll
      for (int j = 0; j < 4; ++j) {
        float c = acc[i][j][r];
        sp += c * asv[j];
        dp += c * adv[j];
        if (row < M) Cb[(size_t)row * N + cb + j * 16] = f2fp8(c);
      }
#pragma unroll
      for (int m = 1; m < 16; m <<= 1) {
        sp += __shfl_xor(sp, m);
        dp += __shfl_xor(dp, m);
      }
      if ((lane & 15) == 0) {
        int rowb = wm + i * 16 + ((lane >> 4) << 2) + r;
        st_sh[0][rowb][wid >> 1] = sp;
        st_sh[1][rowb][wid >> 1] = dp;
      }
    }
  __syncthreads();
  if (tid < 64) {
    int row = row0 + tid;
    if (row < M) {
      asn[(size_t)row * NC + hidx] = st_sh[0][tid][0] + st_sh[0][tid][1];
      adn[(size_t)row * NC + hidx] = st_sh[1][tid][0] + st_sh[1][tid][1];
    }
  }
}

// -------- fp32-A split GEMM (layer 0): 3 MFMA, BM=64, VGPR staging --------
template <int NC>
__global__ __launch_bounds__(256, 2) void gemm_f32a_kernel(
    const float* __restrict__ A, const ushort* __restrict__ Bth,
    const ushort* __restrict__ Btl, unsigned char* __restrict__ Cb,
    const float* __restrict__ a_s, const float* __restrict__ a_d,
    float* __restrict__ asn, float* __restrict__ adn,
    int M, int K) {
  __shared__ s16x8 Ash[4][64], Asl[4][64];
  __shared__ s16x8 Bsh[4][128], Bsl[4][128];
  __shared__ float st_sh[2][64][2];
  int id = blockIdx.x;
  int rs = (id / (8 * NC)) * 8 + (id & 7);
  int row0 = rs * 64;
  if (row0 >= M) return;
  int hidx = (id >> 3) % NC;
  int col0 = hidx * 128;
  int tid = threadIdx.x;
  int am = tid >> 2, aq = tid & 3;
  int bn = tid >> 1, bq = (tid & 1) << 1;
  int lane = tid & 63, wid = tid >> 6;
  int wm = (wid & 1) << 5, wn = (wid >> 1) << 6;
  int fr = lane & 15, fqq = lane >> 4;
  f32x4 acc[2][4] = {};
  const float* Arow = A + (size_t)(row0 + am) * K + aq * 8;
  bool avalid = (row0 + am) < M;
  const ushort* bhp = Bth + (size_t)(col0 + bn) * K + bq * 8;
  const ushort* blp = Btl + (size_t)(col0 + bn) * K + bq * 8;

  for (int k0 = 0; k0 < K; k0 += 32) {
    float v[8];
    if (avalid) {
      float4 t0 = *(const float4*)(Arow + k0);
      float4 t1 = *(const float4*)(Arow + k0 + 4);
      v[0] = t0.x; v[1] = t0.y; v[2] = t0.z; v[3] = t0.w;
      v[4] = t1.x; v[5] = t1.y; v[6] = t1.z; v[7] = t1.w;
    } else {
#pragma unroll
      for (int r = 0; r < 8; ++r) v[r] = 0.f;
    }
    s16x8 hv, lv;
#pragma unroll
    for (int r = 0; r < 8; ++r) {
      ushort h = f2bf(v[r]);
      hv[r] = (short)h;
      lv[r] = (short)f2bf(v[r] - bf2f(h));
    }
    Ash[aq][am] = hv;
    Asl[aq][am] = lv;
    Bsh[bq][bn]     = *(const s16x8*)(bhp + k0);
    Bsh[bq + 1][bn] = *(const s16x8*)(bhp + k0 + 8);
    Bsl[bq][bn]     = *(const s16x8*)(blp + k0);
    Bsl[bq + 1][bn] = *(const s16x8*)(blp + k0 + 8);
    __syncthreads();
    s16x8 ah[2], al[2], bh[4], bl[4];
#pragma unroll
    for (int i = 0; i < 2; ++i) {
      ah[i] = Ash[fqq][wm + i * 16 + fr];
      al[i] = Asl[fqq][wm + i * 16 + fr];
    }
#pragma unroll
    for (int j = 0; j < 4; ++j) {
      bh[j] = Bsh[fqq][wn + j * 16 + fr];
      bl[j] = Bsl[fqq][wn + j * 16 + fr];
    }
#pragma unroll
    for (int i = 0; i < 2; ++i)
#pragma unroll
      for (int j = 0; j < 4; ++j) {
        acc[i][j] = __builtin_amdgcn_mfma_f32_16x16x32_bf16(ah[i], bh[j], acc[i][j], 0, 0, 0);
        acc[i][j] = __builtin_amdgcn_mfma_f32_16x16x32_bf16(ah[i], bl[j], acc[i][j], 0, 0, 0);
        acc[i][j] = __builtin_amdgcn_mfma_f32_16x16x32_bf16(al[i], bh[j], acc[i][j], 0, 0, 0);
      }
    __syncthreads();
  }
  gemm_epilogue<NC>(acc, Cb, a_s, a_d, asn, adn, st_sh, M, row0, col0, hidx,
                    tid, lane, wid, wm, wn, fr);
}

// -------- bf16-A GEMM BM=64 (layer 2): 2 MFMA, VGPR staging ---------------
template <int NC>
__global__ __launch_bounds__(256, 2) void gemm_bf16a_kernel(
    const ushort* __restrict__ A, const ushort* __restrict__ Bth,
    const ushort* __restrict__ Btl, unsigned char* __restrict__ Cb,
    const float* __restrict__ a_s, const float* __restrict__ a_d,
    float* __restrict__ asn, float* __restrict__ adn,
    int M, int K) {
  __shared__ s16x8 Ash[4][64];
  __shared__ s16x8 Bsh[4][128], Bsl[4][128];
  __shared__ float st_sh[2][64][2];
  int id = blockIdx.x;
  int rs = (id / (8 * NC)) * 8 + (id & 7);
  int row0 = rs * 64;
  if (row0 >= M) return;
  int hidx = (id >> 3) % NC;
  int col0 = hidx * 128;
  int tid = threadIdx.x;
  int am = tid >> 2, aq = tid & 3;
  int bn = tid >> 1, bq = (tid & 1) << 1;
  int lane = tid & 63, wid = tid >> 6;
  int wm = (wid & 1) << 5, wn = (wid >> 1) << 6;
  int fr = lane & 15, fqq = lane >> 4;
  f32x4 acc[2][4] = {};
  const ushort* Arow = A + (size_t)(row0 + am) * K + aq * 8;
  bool avalid = (row0 + am) < M;
  const ushort* bhp = Bth + (size_t)(col0 + bn) * K + bq * 8;
  const ushort* blp = Btl + (size_t)(col0 + bn) * K + bq * 8;
  const s16x8 zero8 = {};

  for (int k0 = 0; k0 < K; k0 += 32) {
    Ash[aq][am] = avalid ? *(const s16x8*)(Arow + k0) : zero8;
    Bsh[bq][bn]     = *(const s16x8*)(bhp + k0);
    Bsh[bq + 1][bn] = *(const s16x8*)(bhp + k0 + 8);
    Bsl[bq][bn]     = *(const s16x8*)(blp + k0);
    Bsl[bq + 1][bn] = *(const s16x8*)(blp + k0 + 8);
    __syncthreads();
    s16x8 ah[2], bh[4], bl[4];
#pragma unroll
    for (int i = 0; i < 2; ++i) ah[i] = Ash[fqq][wm + i * 16 + fr];
#pragma unroll
    for (int j = 0; j < 4; ++j) {
      bh[j] = Bsh[fqq][wn + j * 16 + fr];
      bl[j] = Bsl[fqq][wn + j * 16 + fr];
    }
#pragma unroll
    for (int i = 0; i < 2; ++i)
#pragma unroll
      for (int j = 0; j < 4; ++j) {
        acc[i][j] = __builtin_amdgcn_mfma_f32_16x16x32_bf16(ah[i], bh[j], acc[i][j], 0, 0, 0);
        acc[i][j] = __builtin_amdgcn_mfma_f32_16x16x32_bf16(ah[i], bl[j], acc[i][j], 0, 0, 0);
      }
    __syncthreads();
  }
  gemm_epilogue<NC>(acc, Cb, a_s, a_d, asn, adn, st_sh, M, row0, col0, hidx,
                    tid, lane, wid, wm, wn, fr);
}

// -------- bf16-A GEMM BM=128 (layer 1): 2 MFMA, 4x4 tiles/wave ------------
template <int NC>
__global__ __launch_bounds__(256, 2) void gemm_bf16a128_kernel(
    const ushort* __restrict__ A, const ushort* __restrict__ Bth,
    const ushort* __restrict__ Btl, unsigned char* __restrict__ Cb,
    const float* __restrict__ a_s, const float* __restrict__ a_d,
    float* __restrict__ asn, float* __restrict__ adn,
    int M, int K) {
  constexpr int N = NC * 128;
  __shared__ s16x8 Ash[4][128];
  __shared__ s16x8 Bsh[4][128], Bsl[4][128];
  __shared__ float st_sh[2][128][2];
  int id = blockIdx.x;
  int rs = (id / (8 * NC)) * 8 + (id & 7);
  int row0 = rs * 128;
  if (row0 >= M) return;
  int hidx = (id >> 3) % NC;
  int col0 = hidx * 128;
  int tid = threadIdx.x;
  int am = tid >> 1, aq = (tid & 1) << 1;
  int bn = tid >> 1, bq = (tid & 1) << 1;
  int lane = tid & 63, wid = tid >> 6;
  int wm = (wid & 1) << 6, wn = (wid >> 1) << 6;
  int fr = lane & 15, fqq = lane >> 4;
  f32x4 acc[4][4] = {};
  const ushort* Arow = A + (size_t)(row0 + am) * K + aq * 8;
  bool avalid = (row0 + am) < M;
  const ushort* bhp = Bth + (size_t)(col0 + bn) * K + bq * 8;
  const ushort* blp = Btl + (size_t)(col0 + bn) * K + bq * 8;
  const s16x8 zero8 = {};

  for (int k0 = 0; k0 < K; k0 += 32) {
    Ash[aq][am]     = avalid ? *(const s16x8*)(Arow + k0) : zero8;
    Ash[aq + 1][am] = avalid ? *(const s16x8*)(Arow + k0 + 8) : zero8;
    Bsh[bq][bn]     = *(const s16x8*)(bhp + k0);
    Bsh[bq + 1][bn] = *(const s16x8*)(bhp + k0 + 8);
    Bsl[bq][bn]     = *(const s16x8*)(blp + k0);
    Bsl[bq + 1][bn] = *(const s16x8*)(blp + k0 + 8);
    __syncthreads();
    s16x8 ah[4], bh[4], bl[4];
#pragma unroll
    for (int i = 0; i < 4; ++i) ah[i] = Ash[fqq][wm + i * 16 + fr];
#pragma unroll
    for (int j = 0; j < 4; ++j) {
      bh[j] = Bsh[fqq][wn + j * 16 + fr];
      bl[j] = Bsl[fqq][wn + j * 16 + fr];
    }
#pragma unroll
    for (int i = 0; i < 4; ++i)
#pragma unroll
      for (int j = 0; j < 4; ++j) {
        acc[i][j] = __builtin_amdgcn_mfma_f32_16x16x32_bf16(ah[i], bh[j], acc[i][j], 0, 0, 0);
        acc[i][j] = __builtin_amdgcn_mfma_f32_16x16x32_bf16(ah[i], bl[j], acc[i][j], 0, 0, 0);
      }
    __syncthreads();
  }
  float asv[4], adv[4];
#pragma unroll
  for (int j = 0; j < 4; ++j) {
    asv[j] = a_s[hidx * 128 + wn + j * 16 + fr];
    adv[j] = a_d[hidx * 128 + wn + j * 16 + fr];
  }
  int rb = row0 + wm + ((lane >> 4) << 2);
  int cb = col0 + wn + fr;
#pragma unroll
  for (int i = 0; i < 4; ++i)
#pragma unroll
    for (int r = 0; r < 4; ++r) {
      int row = rb + i * 16 + r;
      float sp = 0.f, dp = 0.f;
#pragma unroll
      for (int j = 0; j < 4; ++j) {
        float c = acc[i][j][r];
        sp += c * asv[j];
        dp += c * adv[j];
        if (row < M) Cb[(size_t)row * N + cb + j * 16] = f2fp8(c);
      }
#pragma unroll
      for (int m = 1; m < 16; m <<= 1) {
        sp += __shfl_xor(sp, m);
        dp += __shfl_xor(dp, m);
      }
      if ((lane & 15) == 0) {
        int rowb = wm + i * 16 + ((lane >> 4) << 2) + r;
        st_sh[0][rowb][wid >> 1] = sp;
        st_sh[1][rowb][wid >> 1] = dp;
      }
    }
  __syncthreads();
  if (tid < 128) {
    int row = row0 + tid;
    if (row < M) {
      asn[(size_t)row * NC + hidx] = st_sh[0][tid][0] + st_sh[0][tid][1];
      adn[(size_t)row * NC + hidx] = st_sh[1][tid][0] + st_sh[1][tid][1];
    }
  }
}

// ------- H=4 single-pass agg: wave/node, 8ch/lane, batch-8 fp8, bf16 out ---
__global__ __launch_bounds__(256) void agg4_kernel(
    const unsigned char* __restrict__ xl, const float* __restrict__ asn,
    const float* __restrict__ adn, const int* __restrict__ offsets,
    const int* __restrict__ srcs, const float* __restrict__ bias,
    ushort* __restrict__ out, int n) {
  __shared__ float alpha_sh[4][4][64];   // [wave][head][edge-in-chunk]
  __shared__ int src_sh[4][64];
  int wib = threadIdx.x >> 6, lane = threadIdx.x & 63;
  int nd = blockIdx.x * 4 + wib;
  if (nd >= n) return;
  int beg = offsets[nd], deg = offsets[nd + 1] - beg;
  float4 adl = *(const float4*)&adn[(size_t)nd * 4];
  int ch0 = lane << 3;                   // 8 channels/lane (bytes in fp8)
  int hm = lane >> 4;                    // my head = ch0/128
  float den[4] = {0.f, 0.f, 0.f, 0.f};
  float acc[8] = {};

  for (int j0 = 0; j0 < deg; j0 += 64) {
    int j = j0 + lane;
    int s = 0;
    float w0 = 0.f, w1 = 0.f, w2 = 0.f, w3 = 0.f;
    if (j < deg) {
      s = srcs[beg + j];
      float4 av = *(const float4*)&asn[(size_t)s * 4];
      float e;
      e = av.x + adl.x; e = (e > 0.f) ? e : 0.2f * e; w0 = __expf(fminf(e, 30.f));
      e = av.y + adl.y; e = (e > 0.f) ? e : 0.2f * e; w1 = __expf(fminf(e, 30.f));
      e = av.z + adl.z; e = (e > 0.f) ? e : 0.2f * e; w2 = __expf(fminf(e, 30.f));
      e = av.w + adl.w; e = (e > 0.f) ? e : 0.2f * e; w3 = __expf(fminf(e, 30.f));
      den[0] += w0; den[1] += w1; den[2] += w2; den[3] += w3;
    }
    src_sh[wib][lane] = s;
    alpha_sh[wib][0][lane] = w0;
    alpha_sh[wib][1][lane] = w1;
    alpha_sh[wib][2][lane] = w2;
    alpha_sh[wib][3][lane] = w3;
    __builtin_amdgcn_wave_barrier();
    int cl = min(64, deg - j0);
    int jj = 0;
    for (; jj + 8 <= cl; jj += 8) {
      int4 sv0 = *(const int4*)&src_sh[wib][jj];
      int4 sv1 = *(const int4*)&src_sh[wib][jj + 4];
      float4 av0 = *(const float4*)&alpha_sh[wib][hm][jj];
      float4 av1 = *(const float4*)&alpha_sh[wib][hm][jj + 4];
      uint2 v[8];
      v[0] = *(const uint2*)(xl + (size_t)sv0.x * 512 + ch0);
      v[1] = *(const uint2*)(xl + (size_t)sv0.y * 512 + ch0);
      v[2] = *(const uint2*)(xl + (size_t)sv0.z * 512 + ch0);
      v[3] = *(const uint2*)(xl + (size_t)sv0.w * 512 + ch0);
      v[4] = *(const uint2*)(xl + (size_t)sv1.x * 512 + ch0);
      v[5] = *(const uint2*)(xl + (size_t)sv1.y * 512 + ch0);
      v[6] = *(const uint2*)(xl + (size_t)sv1.z * 512 + ch0);
      v[7] = *(const uint2*)(xl + (size_t)sv1.w * 512 + ch0);
      float a[8] = {av0.x, av0.y, av0.z, av0.w, av1.x, av1.y, av1.z, av1.w};
#pragma unroll
      for (int u = 0; u < 8; ++u) {
        f32x2 c01 = __builtin_amdgcn_cvt_pk_f32_fp8((int)v[u].x, false);
        f32x2 c23 = __builtin_amdgcn_cvt_pk_f32_fp8((int)v[u].x, true);
        f32x2 c45 = __builtin_amdgcn_cvt_pk_f32_fp8((int)v[u].y, false);
        f32x2 c67 = __builtin_amdgcn_cvt_pk_f32_fp8((int)v[u].y, true);
        acc[0] += a[u] * c01[0]; acc[1] += a[u] * c01[1];
        acc[2] += a[u] * c23[0]; acc[3] += a[u] * c23[1];
        acc[4] += a[u] * c45[0]; acc[5] += a[u] * c45[1];
        acc[6] += a[u] * c67[0]; acc[7] += a[u] * c67[1];
      }
    }
    for (; jj < cl; ++jj) {
      int s2 = src_sh[wib][jj];
      float a = alpha_sh[wib][hm][jj];
      uint2 v = *(const uint2*)(xl + (size_t)s2 * 512 + ch0);
      f32x2 c01 = __builtin_amdgcn_cvt_pk_f32_fp8((int)v.x, false);
      f32x2 c23 = __builtin_amdgcn_cvt_pk_f32_fp8((int)v.x, true);
      f32x2 c45 = __builtin_amdgcn_cvt_pk_f32_fp8((int)v.y, false);
      f32x2 c67 = __builtin_amdgcn_cvt_pk_f32_fp8((int)v.y, true);
      acc[0] += a * c01[0]; acc[1] += a * c01[1];
      acc[2] += a * c23[0]; acc[3] += a * c23[1];
      acc[4] += a * c45[0]; acc[5] += a * c45[1];
      acc[6] += a * c67[0]; acc[7] += a * c67[1];
    }
    __builtin_amdgcn_wave_barrier();
  }
  // full-wave reduce of the 4 head denominators
#pragma unroll
  for (int h = 0; h < 4; ++h)
    for (int m = 1; m < 64; m <<= 1) den[h] += __shfl_xor(den[h], m);
  float d = (hm == 0) ? den[0] : (hm == 1) ? den[1] : (hm == 2) ? den[2] : den[3];
  float inv = 1.f / d;
  s16x8 ob;
#pragma unroll
  for (int i = 0; i < 8; ++i)
    ob[i] = (short)f2bf(fmaxf(acc[i] * inv + bias[ch0 + i], 0.f));
  *(s16x8*)(out + (size_t)nd * 512 + ch0) = ob;
}

// ------- H=1 agg + fused mean-pool partial sums (layer 2) ------------------
// 4 waves = 4 nodes per block; block-level LDS reduce -> 128 atomicAdds to g.
__global__ __launch_bounds__(256) void agg1_pool_kernel(
    const unsigned char* __restrict__ xl, const float* __restrict__ asn,
    const float* __restrict__ adn, const int* __restrict__ offsets,
    const int* __restrict__ srcs, const float* __restrict__ bias,
    float* __restrict__ g, int n) {
  __shared__ float alpha_sh[4][64];
  __shared__ int src_sh[4][64];
  __shared__ float red_sh[4][128];
  int wib = threadIdx.x >> 6, lane = threadIdx.x & 63;
  int nd = blockIdx.x * 4 + wib;
  bool valid = nd < n;
  int ch0 = lane << 1;
  float acc0 = 0.f, acc1 = 0.f;

  if (valid) {
    int beg = offsets[nd], deg = offsets[nd + 1] - beg;
    float adl = adn[nd];
    float den = 0.f;
    for (int j0 = 0; j0 < deg; j0 += 64) {
      int j = j0 + lane;
      int s = 0;
      float w = 0.f;
      if (j < deg) {
        s = srcs[beg + j];
        float e = asn[s] + adl;
        e = (e > 0.f) ? e : 0.2f * e;
        w = __expf(fminf(e, 30.f));
        den += w;
      }
      src_sh[wib][lane] = s;
      alpha_sh[wib][lane] = w;
      __builtin_amdgcn_wave_barrier();
      int cl = min(64, deg - j0);
      int jj = 0;
      for (; jj + 4 <= cl; jj += 4) {
        int4 sv = *(const int4*)&src_sh[wib][jj];
        float4 av = *(const float4*)&alpha_sh[wib][jj];
        uint v0 = *(const ushort*)(xl + (size_t)sv.x * 128 + ch0);
        uint v1 = *(const ushort*)(xl + (size_t)sv.y * 128 + ch0);
        uint v2 = *(const ushort*)(xl + (size_t)sv.z * 128 + ch0);
        uint v3 = *(const ushort*)(xl + (size_t)sv.w * 128 + ch0);
        f32x2 c0 = __builtin_amdgcn_cvt_pk_f32_fp8((int)v0, false);
        f32x2 c1 = __builtin_amdgcn_cvt_pk_f32_fp8((int)v1, false);
        f32x2 c2 = __builtin_amdgcn_cvt_pk_f32_fp8((int)v2, false);
        f32x2 c3 = __builtin_amdgcn_cvt_pk_f32_fp8((int)v3, false);
        acc0 += av.x * c0[0]; acc1 += av.x * c0[1];
        acc0 += av.y * c1[0]; acc1 += av.y * c1[1];
        acc0 += av.z * c2[0]; acc1 += av.z * c2[1];
        acc0 += av.w * c3[0]; acc1 += av.w * c3[1];
      }
      for (; jj < cl; ++jj) {
        int s2 = src_sh[wib][jj];
        float a = alpha_sh[wib][jj];
        uint v = *(const ushort*)(xl + (size_t)s2 * 128 + ch0);
        f32x2 c = __builtin_amdgcn_cvt_pk_f32_fp8((int)v, false);
        acc0 += a * c[0]; acc1 += a * c[1];
      }
      __builtin_amdgcn_wave_barrier();
    }
    for (int m = 1; m < 64; m <<= 1) den += __shfl_xor(den, m);
    float inv = 1.f / den;
    acc0 = acc0 * inv + bias[ch0 + 0];
    acc1 = acc1 * inv + bias[ch0 + 1];
  }
  red_sh[wib][ch0] = acc0;
  red_sh[wib][ch0 + 1] = acc1;
  __syncthreads();
  if (threadIdx.x < 128) {
    float s = red_sh[0][threadIdx.x] + red_sh[1][threadIdx.x] +
              red_sh[2][threadIdx.x] + red_sh[3][threadIdx.x];
    atomicAdd(&g[threadIdx.x], s);
  }
}

// ---------------- final MLP ----------------
__global__ void mlp_kernel(const float* __restrict__ g, const float* __restrict__ Wm1,
                           const float* __restrict__ bm1, const float* __restrict__ Wm2,
                           const float* __restrict__ bm2, float* __restrict__ out,
                           float invn) {
  __shared__ float gs[128];
  __shared__ float hs[64];
  int t = threadIdx.x;                 // 64 threads
  gs[t] = g[t] * invn;
  gs[t + 64] = g[t + 64] * invn;
  __syncthreads();
  float acc = bm1[t];
  for (int c = 0; c < 128; ++c) acc += gs[c] * Wm1[c * 64 + t];
  hs[t] = fmaxf(acc, 0.f);
  __syncthreads();
  if (t == 0) {
    float o = bm2[0];
    for (int j = 0; j < 64; ++j) o += hs[j] * Wm2[j];
    out[0] = o;
  }
}

// ---------------------------------------------------------------------------
extern "C" void kernel_launch(void* const* d_in, const int* in_sizes, int n_in,
                              void* d_out, int out_size, void* d_ws, size_t ws_size,
                              hipStream_t stream) {
  const float* x   = (const float*)d_in[0];
  const int*   ei  = (const int*)d_in[1];
  const float* W0  = (const float*)d_in[2];
  const float* as0 = (const float*)d_in[3];
  const float* ad0 = (const float*)d_in[4];
  const float* b0  = (const float*)d_in[5];
  const float* W1  = (const float*)d_in[6];
  const float* as1 = (const float*)d_in[7];
  const float* ad1 = (const float*)d_in[8];
  const float* b1  = (const float*)d_in[9];
  const float* W2  = (const float*)d_in[10];
  const float* as2 = (const float*)d_in[11];
  const float* ad2 = (const float*)d_in[12];
  const float* b2  = (const float*)d_in[13];
  const float* Wm1 = (const float*)d_in[14];
  const float* bm1 = (const float*)d_in[15];
  const float* Wm2 = (const float*)d_in[16];
  const float* bm2 = (const float*)d_in[17];

  const int N = in_sizes[0] / 128;     // 20000
  const int E = in_sizes[1] / 2;       // 320000
  const int ET = E + N;                // with self loops

  // workspace layout
  ushort* hb  = (ushort*)d_ws;                        // N*512 bf16 (h)
  unsigned char* xlb = (unsigned char*)(hb + (size_t)N * 512);  // N*512 fp8 xl
  float*  asn = (float*)(xlb + (size_t)N * 512);      // N*4
  float*  adn = asn + (size_t)N * 4;                  // N*4
  float*  g   = adn + (size_t)N * 4;                  // 128 pool accumulator
  int* counts = (int*)(g + 128);                      // N
  int* cursor = counts + N;                           // N
  int* offs   = cursor + N;                           // N+1
  int* srcs   = offs + N + 1;                         // ET
  int* parts  = srcs + ET;                            // 1024 scan partials
  ushort* w0h = (ushort*)(((uintptr_t)(parts + 1024) + 63) & ~(uintptr_t)63);
  ushort* w0l = w0h + 512 * 128;
  ushort* w1h = w0l + 512 * 128;
  ushort* w1l = w1h + 512 * 512;
  ushort* w2h = w1l + 512 * 512;
  ushort* w2l = w2h + 128 * 512;

  // zero pool accumulator + counts + cursor (contiguous)
  hipMemsetAsync(g, 0, (size_t)(128 + 2 * N) * sizeof(int), stream);

  // prep: wsplit (98304 items) + degree count (ET items), one kernel
  prep_kernel<<<(98304 + ET + 255) / 256, 256, 0, stream>>>(
      W0, W1, W2, w0h, w0l, w1h, w1l, w2h, w2l, ei, counts, E, N);

  // CSR by dst (scan1 -> scan3 w/ self-carry -> scatter)
  int ebl = (ET + 255) / 256;
  int nb = (N + 255) / 256;            // 79 <= 256 (scan3 self-carry limit)
  scan1_kernel<<<nb, 256, 0, stream>>>(counts, parts, N);
  scan3_kernel<<<nb, 256, 0, stream>>>(counts, parts, offs, N);
  scatter_kernel<<<ebl, 256, 0, stream>>>(ei, offs, cursor, srcs, E, N);

  int nwb4 = (N + 3) / 4;              // 4 nodes/block
  int rsn = (N + 63) / 64;             // 313 row strips (BM=64)
  int rsp = ((rsn + 7) / 8) * 8;       // 320
  int blk0 = rsp * 4;                  // NC=4, BM=64 (layer 0)
  int rs128 = (N + 127) / 128;         // 157 row strips (BM=128)
  int rsp128 = ((rs128 + 7) / 8) * 8;  // 160
  int blk1 = rsp128 * 4;               // NC=4, BM=128 (layer 1)
  int blk2 = rsp;                      // NC=1, BM=64 (layer 2)

  // layer 0: fp32 x -> xlb (fp8) + stats
  gemm_f32a_kernel<4><<<blk0, 256, 0, stream>>>(x, w0h, w0l, xlb, as0, ad0,
                                                asn, adn, N, 128);
  agg4_kernel<<<nwb4, 256, 0, stream>>>(xlb, asn, adn, offs, srcs, b0, hb, N);

  // layer 1: bf16 h0 -> xlb (fp8) + stats (BM=128 tile)
  gemm_bf16a128_kernel<4><<<blk1, 256, 0, stream>>>(hb, w1h, w1l, xlb, as1, ad1,
                                                    asn, adn, N, 512);
  agg4_kernel<<<nwb4, 256, 0, stream>>>(xlb, asn, adn, offs, srcs, b1, hb, N);

  // layer 2: bf16 h1 -> xlb (fp8, N*128) + stats; agg1+pool fused -> g
  gemm_bf16a_kernel<1><<<blk2, 256, 0, stream>>>(hb, w2h, w2l, xlb, as2, ad2,
                                                 asn, adn, N, 512);
  agg1_pool_kernel<<<nwb4, 256, 0, stream>>>(xlb, asn, adn, offs, srcs, b2, g, N);

  // MLP
  mlp_kernel<<<1, 64, 0, stream>>>(g, Wm1, bm1, Wm2, bm2, (float*)d_out, 1.0f / (float)N);
}

// Round 16
// 282.323 us; speedup vs baseline: 1.3844x; 1.3844x over previous
//
#include <hip/hip_runtime.h>
#include <math.h>

// ---------------------------------------------------------------------------
// GAT pipeline (R16 = R15 + sharded pool accumulator):
//   prep (wsplit + degree count) -> scan1 -> scan3(self-carry) -> scatter
//   L0: fp32-A split-bf16 MFMA GEMM (3 mfma, BM=64) -> xl fp8 + stats
//   L1: bf16-A GEMM BM=128 (2 mfma);  L2: bf16-A GEMM BM=64
//   agg4 x2: single-pass exp gather (fp8, batch-8), bf16 h out
//   agg1+pool fused -> g_part[64][128] (78 colliders/addr); mlp folds 64x128
// R15 post-mortem: FAILED — 5000 blocks x 128 atomicAdds on the SAME 128
//   words serialized (~50cyc/op x 5000/addr = 126us, HBM 1.3%, VALU 5.6%).
//   Rule: same-address atomic colliders must stay ~O(100).
// R16: shard accumulator 64 ways (blockIdx%64) -> 78 colliders/addr, like
//   the proven 128-block pool; mlp pre-folds the 64 partial vectors.
// ---------------------------------------------------------------------------

typedef float f32x4 __attribute__((ext_vector_type(4)));
typedef float f32x2 __attribute__((ext_vector_type(2)));
typedef short s16x8 __attribute__((ext_vector_type(8)));
typedef short s16x4 __attribute__((ext_vector_type(4)));

__device__ inline ushort f2bf(float f) {
  unsigned u = __float_as_uint(f);
  u += 0x7FFF + ((u >> 16) & 1);          // round-to-nearest-even
  return (ushort)(u >> 16);
}
__device__ inline float bf2f(ushort h) { return __uint_as_float((unsigned)h << 16); }
__device__ inline unsigned char f2fp8(float f) {
  int p = __builtin_amdgcn_cvt_pk_fp8_f32(f, f, 0, false);
  return (unsigned char)(p & 0xFF);
}

// ------- prep: weight transpose/split (idx<98304) + degree count (rest) ----
__global__ void prep_kernel(
    const float* __restrict__ W0, const float* __restrict__ W1,
    const float* __restrict__ W2, ushort* __restrict__ w0h, ushort* __restrict__ w0l,
    ushort* __restrict__ w1h, ushort* __restrict__ w1l, ushort* __restrict__ w2h,
    ushort* __restrict__ w2l, const int* __restrict__ ei, int* __restrict__ counts,
    int E, int n) {
  int idx = blockIdx.x * 256 + threadIdx.x;
  if (idx >= 98304) {
    int t = idx - 98304;
    if (t < E)          atomicAdd(&counts[ei[E + t]], 1);
    else if (t < E + n) atomicAdd(&counts[t - E], 1);
    return;
  }
  const float* W; ushort *th, *tl; int K, N;
  if (idx < 16384)      { W = W0; th = w0h; tl = w0l; K = 128; N = 512; }
  else if (idx < 81920) { idx -= 16384; W = W1; th = w1h; tl = w1l; K = 512; N = 512; }
  else                  { idx -= 81920; W = W2; th = w2h; tl = w2l; K = 512; N = 128; }
  int nn = idx % N;
  int k4 = (idx / N) << 2;
  s16x4 hv, lv;
#pragma unroll
  for (int r = 0; r < 4; ++r) {
    float w = W[(size_t)(k4 + r) * N + nn];
    ushort h = f2bf(w);
    hv[r] = (short)h;
    lv[r] = (short)f2bf(w - bf2f(h));
  }
  *(s16x4*)&th[(size_t)nn * K + k4] = hv;
  *(s16x4*)&tl[(size_t)nn * K + k4] = lv;
}

__global__ void scan1_kernel(const int* __restrict__ counts, int* __restrict__ partials,
                             int n) {
  __shared__ int sd[4];
  int i = blockIdx.x * 256 + threadIdx.x;
  int v = (i < n) ? counts[i] : 0;
  for (int m = 32; m; m >>= 1) v += __shfl_xor(v, m);
  if ((threadIdx.x & 63) == 0) sd[threadIdx.x >> 6] = v;
  __syncthreads();
  if (threadIdx.x == 0) partials[blockIdx.x] = sd[0] + sd[1] + sd[2] + sd[3];
}

// scan3 with self-computed carry: partials are RAW per-block sums; each block
// reduces partials[0..blockIdx.x) itself (nb <= 256).
__global__ void scan3_kernel(const int* __restrict__ counts, const int* __restrict__ partials,
                             int* __restrict__ offsets, int n) {
  __shared__ int sd[256];
  __shared__ int cw[4];
  __shared__ int carry_sh;
  int t = threadIdx.x;
  int pv = (t < blockIdx.x) ? partials[t] : 0;
  for (int m = 32; m; m >>= 1) pv += __shfl_xor(pv, m);
  if ((t & 63) == 0) cw[t >> 6] = pv;
  __syncthreads();
  if (t == 0) carry_sh = cw[0] + cw[1] + cw[2] + cw[3];
  int i = blockIdx.x * 256 + t;
  int v = (i < n) ? counts[i] : 0;
  sd[t] = v;
  __syncthreads();
  for (int off = 1; off < 256; off <<= 1) {
    int u = (t >= off) ? sd[t - off] : 0;
    __syncthreads();
    sd[t] += u;
    __syncthreads();
  }
  int carry = carry_sh;
  if (i < n) {
    offsets[i] = carry + sd[t] - v;
    if (i == n - 1) offsets[n] = carry + sd[t];
  }
}

__global__ void scatter_kernel(const int* __restrict__ ei, const int* __restrict__ offsets,
                               int* __restrict__ cursor, int* __restrict__ srcs,
                               int E, int n) {
  int t = blockIdx.x * blockDim.x + threadIdx.x;
  int s, d;
  if (t < E)          { s = ei[t]; d = ei[E + t]; }
  else if (t < E + n) { s = t - E; d = s; }
  else return;
  int pos = offsets[d] + atomicAdd(&cursor[d], 1);
  srcs[pos] = s;
}

// ---------------- shared GEMM epilogue (fp8 store + fused stats) ----------
template <int NC>
__device__ inline void gemm_epilogue(
    f32x4 (&acc)[2][4], unsigned char* __restrict__ Cb, const float* __restrict__ a_s,
    const float* __restrict__ a_d, float* __restrict__ asn, float* __restrict__ adn,
    float (*st_sh)[64][2], int M, int row0, int col0, int hidx,
    int tid, int lane, int wid, int wm, int wn, int fr) {
  constexpr int N = NC * 128;
  float asv[4], adv[4];
#pragma unroll
  for (int j = 0; j < 4; ++j) {
    asv[j] = a_s[hidx * 128 + wn + j * 16 + fr];
    adv[j] = a_d[hidx * 128 + wn + j * 16 + fr];
  }
  int rb = row0 + wm + ((lane >> 4) << 2);
  int cb = col0 + wn + fr;
#pragma unroll
  for (int i = 0; i < 2; ++i)
#pragma unroll
    for (int r = 0; r < 4; ++r) {
      int row = rb + i * 16 + r;
      float sp = 0.f, dp = 0.f;
#pragma unroll
      for (int j = 0; j < 4; ++j) {
        float c = acc[i][j][r];
        sp += c * asv[j];
        dp += c * adv[j];
        if (row < M) Cb[(size_t)row * N + cb + j * 16] = f2fp8(c);
      }
#pragma unroll
      for (int m = 1; m < 16; m <<= 1) {
        sp += __shfl_xor(sp, m);
        dp += __shfl_xor(dp, m);
      }
      if ((lane & 15) == 0) {
        int rowb = wm + i * 16 + ((lane >> 4) << 2) + r;
        st_sh[0][rowb][wid >> 1] = sp;
        st_sh[1][rowb][wid >> 1] = dp;
      }
    }
  __syncthreads();
  if (tid < 64) {
    int row = row0 + tid;
    if (row < M) {
      asn[(size_t)row * NC + hidx] = st_sh[0][tid][0] + st_sh[0][tid][1];
      adn[(size_t)row * NC + hidx] = st_sh[1][tid][0] + st_sh[1][tid][1];
    }
  }
}

// -------- fp32-A split GEMM (layer 0): 3 MFMA, BM=64, VGPR staging --------
template <int NC>
__global__ __launch_bounds__(256, 2) void gemm_f32a_kernel(
    const float* __restrict__ A, const ushort* __restrict__ Bth,
    const ushort* __restrict__ Btl, unsigned char* __restrict__ Cb,
    const float* __restrict__ a_s, const float* __restrict__ a_d,
    float* __restrict__ asn, float* __restrict__ adn,
    int M, int K) {
  __shared__ s16x8 Ash[4][64], Asl[4][64];
  __shared__ s16x8 Bsh[4][128], Bsl[4][128];
  __shared__ float st_sh[2][64][2];
  int id = blockIdx.x;
  int rs = (id / (8 * NC)) * 8 + (id & 7);
  int row0 = rs * 64;
  if (row0 >= M) return;
  int hidx = (id >> 3) % NC;
  int col0 = hidx * 128;
  int tid = threadIdx.x;
  int am = tid >> 2, aq = tid & 3;
  int bn = tid >> 1, bq = (tid & 1) << 1;
  int lane = tid & 63, wid = tid >> 6;
  int wm = (wid & 1) << 5, wn = (wid >> 1) << 6;
  int fr = lane & 15, fqq = lane >> 4;
  f32x4 acc[2][4] = {};
  const float* Arow = A + (size_t)(row0 + am) * K + aq * 8;
  bool avalid = (row0 + am) < M;
  const ushort* bhp = Bth + (size_t)(col0 + bn) * K + bq * 8;
  const ushort* blp = Btl + (size_t)(col0 + bn) * K + bq * 8;

  for (int k0 = 0; k0 < K; k0 += 32) {
    float v[8];
    if (avalid) {
      float4 t0 = *(const float4*)(Arow + k0);
      float4 t1 = *(const float4*)(Arow + k0 + 4);
      v[0] = t0.x; v[1] = t0.y; v[2] = t0.z; v[3] = t0.w;
      v[4] = t1.x; v[5] = t1.y; v[6] = t1.z; v[7] = t1.w;
    } else {
#pragma unroll
      for (int r = 0; r < 8; ++r) v[r] = 0.f;
    }
    s16x8 hv, lv;
#pragma unroll
    for (int r = 0; r < 8; ++r) {
      ushort h = f2bf(v[r]);
      hv[r] = (short)h;
      lv[r] = (short)f2bf(v[r] - bf2f(h));
    }
    Ash[aq][am] = hv;
    Asl[aq][am] = lv;
    Bsh[bq][bn]     = *(const s16x8*)(bhp + k0);
    Bsh[bq + 1][bn] = *(const s16x8*)(bhp + k0 + 8);
    Bsl[bq][bn]     = *(const s16x8*)(blp + k0);
    Bsl[bq + 1][bn] = *(const s16x8*)(blp + k0 + 8);
    __syncthreads();
    s16x8 ah[2], al[2], bh[4], bl[4];
#pragma unroll
    for (int i = 0; i < 2; ++i) {
      ah[i] = Ash[fqq][wm + i * 16 + fr];
      al[i] = Asl[fqq][wm + i * 16 + fr];
    }
#pragma unroll
    for (int j = 0; j < 4; ++j) {
      bh[j] = Bsh[fqq][wn + j * 16 + fr];
      bl[j] = Bsl[fqq][wn + j * 16 + fr];
    }
#pragma unroll
    for (int i = 0; i < 2; ++i)
#pragma unroll
      for (int j = 0; j < 4; ++j) {
        acc[i][j] = __builtin_amdgcn_mfma_f32_16x16x32_bf16(ah[i], bh[j], acc[i][j], 0, 0, 0);
        acc[i][j] = __builtin_amdgcn_mfma_f32_16x16x32_bf16(ah[i], bl[j], acc[i][j], 0, 0, 0);
        acc[i][j] = __builtin_amdgcn_mfma_f32_16x16x32_bf16(al[i], bh[j], acc[i][j], 0, 0, 0);
      }
    __syncthreads();
  }
  gemm_epilogue<NC>(acc, Cb, a_s, a_d, asn, adn, st_sh, M, row0, col0, hidx,
                    tid, lane, wid, wm, wn, fr);
}

// -------- bf16-A GEMM BM=64 (layer 2): 2 MFMA, VGPR staging ---------------
template <int NC>
__global__ __launch_bounds__(256, 2) void gemm_bf16a_kernel(
    const ushort* __restrict__ A, const ushort* __restrict__ Bth,
    const ushort* __restrict__ Btl, unsigned char* __restrict__ Cb,
    const float* __restrict__ a_s, const float* __restrict__ a_d,
    float* __restrict__ asn, float* __restrict__ adn,
    int M, int K) {
  __shared__ s16x8 Ash[4][64];
  __shared__ s16x8 Bsh[4][128], Bsl[4][128];
  __shared__ float st_sh[2][64][2];
  int id = blockIdx.x;
  int rs = (id / (8 * NC)) * 8 + (id & 7);
  int row0 = rs * 64;
  if (row0 >= M) return;
  int hidx = (id >> 3) % NC;
  int col0 = hidx * 128;
  int tid = threadIdx.x;
  int am = tid >> 2, aq = tid & 3;
  int bn = tid >> 1, bq = (tid & 1) << 1;
  int lane = tid & 63, wid = tid >> 6;
  int wm = (wid & 1) << 5, wn = (wid >> 1) << 6;
  int fr = lane & 15, fqq = lane >> 4;
  f32x4 acc[2][4] = {};
  const ushort* Arow = A + (size_t)(row0 + am) * K + aq * 8;
  bool avalid = (row0 + am) < M;
  const ushort* bhp = Bth + (size_t)(col0 + bn) * K + bq * 8;
  const ushort* blp = Btl + (size_t)(col0 + bn) * K + bq * 8;
  const s16x8 zero8 = {};

  for (int k0 = 0; k0 < K; k0 += 32) {
    Ash[aq][am] = avalid ? *(const s16x8*)(Arow + k0) : zero8;
    Bsh[bq][bn]     = *(const s16x8*)(bhp + k0);
    Bsh[bq + 1][bn] = *(const s16x8*)(bhp + k0 + 8);
    Bsl[bq][bn]     = *(const s16x8*)(blp + k0);
    Bsl[bq + 1][bn] = *(const s16x8*)(blp + k0 + 8);
    __syncthreads();
    s16x8 ah[2], bh[4], bl[4];
#pragma unroll
    for (int i = 0; i < 2; ++i) ah[i] = Ash[fqq][wm + i * 16 + fr];
#pragma unroll
    for (int j = 0; j < 4; ++j) {
      bh[j] = Bsh[fqq][wn + j * 16 + fr];
      bl[j] = Bsl[fqq][wn + j * 16 + fr];
    }
#pragma unroll
    for (int i = 0; i < 2; ++i)
#pragma unroll
      for (int j = 0; j < 4; ++j) {
        acc[i][j] = __builtin_amdgcn_mfma_f32_16x16x32_bf16(ah[i], bh[j], acc[i][j], 0, 0, 0);
        acc[i][j] = __builtin_amdgcn_mfma_f32_16x16x32_bf16(ah[i], bl[j], acc[i][j], 0, 0, 0);
      }
    __syncthreads();
  }
  gemm_epilogue<NC>(acc, Cb, a_s, a_d, asn, adn, st_sh, M, row0, col0, hidx,
                    tid, lane, wid, wm, wn, fr);
}

// -------- bf16-A GEMM BM=128 (layer 1): 2 MFMA, 4x4 tiles/wave ------------
template <int NC>
__global__ __launch_bounds__(256, 2) void gemm_bf16a128_kernel(
    const ushort* __restrict__ A, const ushort* __restrict__ Bth,
    const ushort* __restrict__ Btl, unsigned char* __restrict__ Cb,
    const float* __restrict__ a_s, const float* __restrict__ a_d,
    float* __restrict__ asn, float* __restrict__ adn,
    int M, int K) {
  constexpr int N = NC * 128;
  __shared__ s16x8 Ash[4][128];
  __shared__ s16x8 Bsh[4][128], Bsl[4][128];
  __shared__ float st_sh[2][128][2];
  int id = blockIdx.x;
  int rs = (id / (8 * NC)) * 8 + (id & 7);
  int row0 = rs * 128;
  if (row0 >= M) return;
  int hidx = (id >> 3) % NC;
  int col0 = hidx * 128;
  int tid = threadIdx.x;
  int am = tid >> 1, aq = (tid & 1) << 1;
  int bn = tid >> 1, bq = (tid & 1) << 1;
  int lane = tid & 63, wid = tid >> 6;
  int wm = (wid & 1) << 6, wn = (wid >> 1) << 6;
  int fr = lane & 15, fqq = lane >> 4;
  f32x4 acc[4][4] = {};
  const ushort* Arow = A + (size_t)(row0 + am) * K + aq * 8;
  bool avalid = (row0 + am) < M;
  const ushort* bhp = Bth + (size_t)(col0 + bn) * K + bq * 8;
  const ushort* blp = Btl + (size_t)(col0 + bn) * K + bq * 8;
  const s16x8 zero8 = {};

  for (int k0 = 0; k0 < K; k0 += 32) {
    Ash[aq][am]     = avalid ? *(const s16x8*)(Arow + k0) : zero8;
    Ash[aq + 1][am] = avalid ? *(const s16x8*)(Arow + k0 + 8) : zero8;
    Bsh[bq][bn]     = *(const s16x8*)(bhp + k0);
    Bsh[bq + 1][bn] = *(const s16x8*)(bhp + k0 + 8);
    Bsl[bq][bn]     = *(const s16x8*)(blp + k0);
    Bsl[bq + 1][bn] = *(const s16x8*)(blp + k0 + 8);
    __syncthreads();
    s16x8 ah[4], bh[4], bl[4];
#pragma unroll
    for (int i = 0; i < 4; ++i) ah[i] = Ash[fqq][wm + i * 16 + fr];
#pragma unroll
    for (int j = 0; j < 4; ++j) {
      bh[j] = Bsh[fqq][wn + j * 16 + fr];
      bl[j] = Bsl[fqq][wn + j * 16 + fr];
    }
#pragma unroll
    for (int i = 0; i < 4; ++i)
#pragma unroll
      for (int j = 0; j < 4; ++j) {
        acc[i][j] = __builtin_amdgcn_mfma_f32_16x16x32_bf16(ah[i], bh[j], acc[i][j], 0, 0, 0);
        acc[i][j] = __builtin_amdgcn_mfma_f32_16x16x32_bf16(ah[i], bl[j], acc[i][j], 0, 0, 0);
      }
    __syncthreads();
  }
  float asv[4], adv[4];
#pragma unroll
  for (int j = 0; j < 4; ++j) {
    asv[j] = a_s[hidx * 128 + wn + j * 16 + fr];
    adv[j] = a_d[hidx * 128 + wn + j * 16 + fr];
  }
  int rb = row0 + wm + ((lane >> 4) << 2);
  int cb = col0 + wn + fr;
#pragma unroll
  for (int i = 0; i < 4; ++i)
#pragma unroll
    for (int r = 0; r < 4; ++r) {
      int row = rb + i * 16 + r;
      float sp = 0.f, dp = 0.f;
#pragma unroll
      for (int j = 0; j < 4; ++j) {
        float c = acc[i][j][r];
        sp += c * asv[j];
        dp += c * adv[j];
        if (row < M) Cb[(size_t)row * N + cb + j * 16] = f2fp8(c);
      }
#pragma unroll
      for (int m = 1; m < 16; m <<= 1) {
        sp += __shfl_xor(sp, m);
        dp += __shfl_xor(dp, m);
      }
      if ((lane & 15) == 0) {
        int rowb = wm + i * 16 + ((lane >> 4) << 2) + r;
        st_sh[0][rowb][wid >> 1] = sp;
        st_sh[1][rowb][wid >> 1] = dp;
      }
    }
  __syncthreads();
  if (tid < 128) {
    int row = row0 + tid;
    if (row < M) {
      asn[(size_t)row * NC + hidx] = st_sh[0][tid][0] + st_sh[0][tid][1];
      adn[(size_t)row * NC + hidx] = st_sh[1][tid][0] + st_sh[1][tid][1];
    }
  }
}

// ------- H=4 single-pass agg: wave/node, 8ch/lane, batch-8 fp8, bf16 out ---
__global__ __launch_bounds__(256) void agg4_kernel(
    const unsigned char* __restrict__ xl, const float* __restrict__ asn,
    const float* __restrict__ adn, const int* __restrict__ offsets,
    const int* __restrict__ srcs, const float* __restrict__ bias,
    ushort* __restrict__ out, int n) {
  __shared__ float alpha_sh[4][4][64];   // [wave][head][edge-in-chunk]
  __shared__ int src_sh[4][64];
  int wib = threadIdx.x >> 6, lane = threadIdx.x & 63;
  int nd = blockIdx.x * 4 + wib;
  if (nd >= n) return;
  int beg = offsets[nd], deg = offsets[nd + 1] - beg;
  float4 adl = *(const float4*)&adn[(size_t)nd * 4];
  int ch0 = lane << 3;                   // 8 channels/lane (bytes in fp8)
  int hm = lane >> 4;                    // my head = ch0/128
  float den[4] = {0.f, 0.f, 0.f, 0.f};
  float acc[8] = {};

  for (int j0 = 0; j0 < deg; j0 += 64) {
    int j = j0 + lane;
    int s = 0;
    float w0 = 0.f, w1 = 0.f, w2 = 0.f, w3 = 0.f;
    if (j < deg) {
      s = srcs[beg + j];
      float4 av = *(const float4*)&asn[(size_t)s * 4];
      float e;
      e = av.x + adl.x; e = (e > 0.f) ? e : 0.2f * e; w0 = __expf(fminf(e, 30.f));
      e = av.y + adl.y; e = (e > 0.f) ? e : 0.2f * e; w1 = __expf(fminf(e, 30.f));
      e = av.z + adl.z; e = (e > 0.f) ? e : 0.2f * e; w2 = __expf(fminf(e, 30.f));
      e = av.w + adl.w; e = (e > 0.f) ? e : 0.2f * e; w3 = __expf(fminf(e, 30.f));
      den[0] += w0; den[1] += w1; den[2] += w2; den[3] += w3;
    }
    src_sh[wib][lane] = s;
    alpha_sh[wib][0][lane] = w0;
    alpha_sh[wib][1][lane] = w1;
    alpha_sh[wib][2][lane] = w2;
    alpha_sh[wib][3][lane] = w3;
    __builtin_amdgcn_wave_barrier();
    int cl = min(64, deg - j0);
    int jj = 0;
    for (; jj + 8 <= cl; jj += 8) {
      int4 sv0 = *(const int4*)&src_sh[wib][jj];
      int4 sv1 = *(const int4*)&src_sh[wib][jj + 4];
      float4 av0 = *(const float4*)&alpha_sh[wib][hm][jj];
      float4 av1 = *(const float4*)&alpha_sh[wib][hm][jj + 4];
      uint2 v[8];
      v[0] = *(const uint2*)(xl + (size_t)sv0.x * 512 + ch0);
      v[1] = *(const uint2*)(xl + (size_t)sv0.y * 512 + ch0);
      v[2] = *(const uint2*)(xl + (size_t)sv0.z * 512 + ch0);
      v[3] = *(const uint2*)(xl + (size_t)sv0.w * 512 + ch0);
      v[4] = *(const uint2*)(xl + (size_t)sv1.x * 512 + ch0);
      v[5] = *(const uint2*)(xl + (size_t)sv1.y * 512 + ch0);
      v[6] = *(const uint2*)(xl + (size_t)sv1.z * 512 + ch0);
      v[7] = *(const uint2*)(xl + (size_t)sv1.w * 512 + ch0);
      float a[8] = {av0.x, av0.y, av0.z, av0.w, av1.x, av1.y, av1.z, av1.w};
#pragma unroll
      for (int u = 0; u < 8; ++u) {
        f32x2 c01 = __builtin_amdgcn_cvt_pk_f32_fp8((int)v[u].x, false);
        f32x2 c23 = __builtin_amdgcn_cvt_pk_f32_fp8((int)v[u].x, true);
        f32x2 c45 = __builtin_amdgcn_cvt_pk_f32_fp8((int)v[u].y, false);
        f32x2 c67 = __builtin_amdgcn_cvt_pk_f32_fp8((int)v[u].y, true);
        acc[0] += a[u] * c01[0]; acc[1] += a[u] * c01[1];
        acc[2] += a[u] * c23[0]; acc[3] += a[u] * c23[1];
        acc[4] += a[u] * c45[0]; acc[5] += a[u] * c45[1];
        acc[6] += a[u] * c67[0]; acc[7] += a[u] * c67[1];
      }
    }
    for (; jj < cl; ++jj) {
      int s2 = src_sh[wib][jj];
      float a = alpha_sh[wib][hm][jj];
      uint2 v = *(const uint2*)(xl + (size_t)s2 * 512 + ch0);
      f32x2 c01 = __builtin_amdgcn_cvt_pk_f32_fp8((int)v.x, false);
      f32x2 c23 = __builtin_amdgcn_cvt_pk_f32_fp8((int)v.x, true);
      f32x2 c45 = __builtin_amdgcn_cvt_pk_f32_fp8((int)v.y, false);
      f32x2 c67 = __builtin_amdgcn_cvt_pk_f32_fp8((int)v.y, true);
      acc[0] += a * c01[0]; acc[1] += a * c01[1];
      acc[2] += a * c23[0]; acc[3] += a * c23[1];
      acc[4] += a * c45[0]; acc[5] += a * c45[1];
      acc[6] += a * c67[0]; acc[7] += a * c67[1];
    }
    __builtin_amdgcn_wave_barrier();
  }
  // full-wave reduce of the 4 head denominators
#pragma unroll
  for (int h = 0; h < 4; ++h)
    for (int m = 1; m < 64; m <<= 1) den[h] += __shfl_xor(den[h], m);
  float d = (hm == 0) ? den[0] : (hm == 1) ? den[1] : (hm == 2) ? den[2] : den[3];
  float inv = 1.f / d;
  s16x8 ob;
#pragma unroll
  for (int i = 0; i < 8; ++i)
    ob[i] = (short)f2bf(fmaxf(acc[i] * inv + bias[ch0 + i], 0.f));
  *(s16x8*)(out + (size_t)nd * 512 + ch0) = ob;
}

// ------- H=1 agg + fused mean-pool (sharded accumulator) -------------------
// Block reduce -> atomicAdd into g_part[blockIdx%64][128] (~78 colliders/addr)
__global__ __launch_bounds__(256) void agg1_pool_kernel(
    const unsigned char* __restrict__ xl, const float* __restrict__ asn,
    const float* __restrict__ adn, const int* __restrict__ offsets,
    const int* __restrict__ srcs, const float* __restrict__ bias,
    float* __restrict__ g_part, int n) {
  __shared__ float alpha_sh[4][64];
  __shared__ int src_sh[4][64];
  __shared__ float red_sh[4][128];
  int wib = threadIdx.x >> 6, lane = threadIdx.x & 63;
  int nd = blockIdx.x * 4 + wib;
  bool valid = nd < n;
  int ch0 = lane << 1;
  float acc0 = 0.f, acc1 = 0.f;

  if (valid) {
    int beg = offsets[nd], deg = offsets[nd + 1] - beg;
    float adl = adn[nd];
    float den = 0.f;
    for (int j0 = 0; j0 < deg; j0 += 64) {
      int j = j0 + lane;
      int s = 0;
      float w = 0.f;
      if (j < deg) {
        s = srcs[beg + j];
        float e = asn[s] + adl;
        e = (e > 0.f) ? e : 0.2f * e;
        w = __expf(fminf(e, 30.f));
        den += w;
      }
      src_sh[wib][lane] = s;
      alpha_sh[wib][lane] = w;
      __builtin_amdgcn_wave_barrier();
      int cl = min(64, deg - j0);
      int jj = 0;
      for (; jj + 4 <= cl; jj += 4) {
        int4 sv = *(const int4*)&src_sh[wib][jj];
        float4 av = *(const float4*)&alpha_sh[wib][jj];
        uint v0 = *(const ushort*)(xl + (size_t)sv.x * 128 + ch0);
        uint v1 = *(const ushort*)(xl + (size_t)sv.y * 128 + ch0);
        uint v2 = *(const ushort*)(xl + (size_t)sv.z * 128 + ch0);
        uint v3 = *(const ushort*)(xl + (size_t)sv.w * 128 + ch0);
        f32x2 c0 = __builtin_amdgcn_cvt_pk_f32_fp8((int)v0, false);
        f32x2 c1 = __builtin_amdgcn_cvt_pk_f32_fp8((int)v1, false);
        f32x2 c2 = __builtin_amdgcn_cvt_pk_f32_fp8((int)v2, false);
        f32x2 c3 = __builtin_amdgcn_cvt_pk_f32_fp8((int)v3, false);
        acc0 += av.x * c0[0]; acc1 += av.x * c0[1];
        acc0 += av.y * c1[0]; acc1 += av.y * c1[1];
        acc0 += av.z * c2[0]; acc1 += av.z * c2[1];
        acc0 += av.w * c3[0]; acc1 += av.w * c3[1];
      }
      for (; jj < cl; ++jj) {
        int s2 = src_sh[wib][jj];
        float a = alpha_sh[wib][jj];
        uint v = *(const ushort*)(xl + (size_t)s2 * 128 + ch0);
        f32x2 c = __builtin_amdgcn_cvt_pk_f32_fp8((int)v, false);
        acc0 += a * c[0]; acc1 += a * c[1];
      }
      __builtin_amdgcn_wave_barrier();
    }
    for (int m = 1; m < 64; m <<= 1) den += __shfl_xor(den, m);
    float inv = 1.f / den;
    acc0 = acc0 * inv + bias[ch0 + 0];
    acc1 = acc1 * inv + bias[ch0 + 1];
  }
  red_sh[wib][ch0] = acc0;
  red_sh[wib][ch0 + 1] = acc1;
  __syncthreads();
  if (threadIdx.x < 128) {
    float s = red_sh[0][threadIdx.x] + red_sh[1][threadIdx.x] +
              red_sh[2][threadIdx.x] + red_sh[3][threadIdx.x];
    atomicAdd(&g_part[(blockIdx.x & 63) * 128 + threadIdx.x], s);
  }
}

// ---------------- final MLP (folds 64 sharded partials first) --------------
__global__ void mlp_kernel(const float* __restrict__ g_part,
                           const float* __restrict__ Wm1, const float* __restrict__ bm1,
                           const float* __restrict__ Wm2, const float* __restrict__ bm2,
                           float* __restrict__ out, float invn) {
  __shared__ float gs[128];
  __shared__ float hs[64];
  int t = threadIdx.x;                 // 128 threads
  float s = 0.f;
  for (int k = 0; k < 64; ++k) s += g_part[k * 128 + t];
  gs[t] = s * invn;
  __syncthreads();
  if (t < 64) {
    float acc = bm1[t];
    for (int c = 0; c < 128; ++c) acc += gs[c] * Wm1[c * 64 + t];
    hs[t] = fmaxf(acc, 0.f);
  }
  __syncthreads();
  if (t == 0) {
    float o = bm2[0];
    for (int j = 0; j < 64; ++j) o += hs[j] * Wm2[j];
    out[0] = o;
  }
}

// ---------------------------------------------------------------------------
extern "C" void kernel_launch(void* const* d_in, const int* in_sizes, int n_in,
                              void* d_out, int out_size, void* d_ws, size_t ws_size,
                              hipStream_t stream) {
  const float* x   = (const float*)d_in[0];
  const int*   ei  = (const int*)d_in[1];
  const float* W0  = (const float*)d_in[2];
  const float* as0 = (const float*)d_in[3];
  const float* ad0 = (const float*)d_in[4];
  const float* b0  = (const float*)d_in[5];
  const float* W1  = (const float*)d_in[6];
  const float* as1 = (const float*)d_in[7];
  const float* ad1 = (const float*)d_in[8];
  const float* b1  = (const float*)d_in[9];
  const float* W2  = (const float*)d_in[10];
  const float* as2 = (const float*)d_in[11];
  const float* ad2 = (const float*)d_in[12];
  const float* b2  = (const float*)d_in[13];
  const float* Wm1 = (const float*)d_in[14];
  const float* bm1 = (const float*)d_in[15];
  const float* Wm2 = (const float*)d_in[16];
  const float* bm2 = (const float*)d_in[17];

  const int N = in_sizes[0] / 128;     // 20000
  const int E = in_sizes[1] / 2;       // 320000
  const int ET = E + N;                // with self loops

  // workspace layout
  ushort* hb  = (ushort*)d_ws;                        // N*512 bf16 (h)
  unsigned char* xlb = (unsigned char*)(hb + (size_t)N * 512);  // N*512 fp8 xl
  float*  asn = (float*)(xlb + (size_t)N * 512);      // N*4
  float*  adn = asn + (size_t)N * 4;                  // N*4
  float*  gp  = adn + (size_t)N * 4;                  // 64*128 pool shards
  int* counts = (int*)(gp + 64 * 128);                // N
  int* cursor = counts + N;                           // N
  int* offs   = cursor + N;                           // N+1
  int* srcs   = offs + N + 1;                         // ET
  int* parts  = srcs + ET;                            // 1024 scan partials
  ushort* w0h = (ushort*)(((uintptr_t)(parts + 1024) + 63) & ~(uintptr_t)63);
  ushort* w0l = w0h + 512 * 128;
  ushort* w1h = w0l + 512 * 128;
  ushort* w1l = w1h + 512 * 512;
  ushort* w2h = w1l + 512 * 512;
  ushort* w2l = w2h + 128 * 512;

  // zero pool shards + counts + cursor (contiguous)
  hipMemsetAsync(gp, 0, (size_t)(64 * 128 + 2 * N) * sizeof(int), stream);

  // prep: wsplit (98304 items) + degree count (ET items), one kernel
  prep_kernel<<<(98304 + ET + 255) / 256, 256, 0, stream>>>(
      W0, W1, W2, w0h, w0l, w1h, w1l, w2h, w2l, ei, counts, E, N);

  // CSR by dst (scan1 -> scan3 w/ self-carry -> scatter)
  int ebl = (ET + 255) / 256;
  int nb = (N + 255) / 256;            // 79 <= 256 (scan3 self-carry limit)
  scan1_kernel<<<nb, 256, 0, stream>>>(counts, parts, N);
  scan3_kernel<<<nb, 256, 0, stream>>>(counts, parts, offs, N);
  scatter_kernel<<<ebl, 256, 0, stream>>>(ei, offs, cursor, srcs, E, N);

  int nwb4 = (N + 3) / 4;              // 4 nodes/block
  int rsn = (N + 63) / 64;             // 313 row strips (BM=64)
  int rsp = ((rsn + 7) / 8) * 8;       // 320
  int blk0 = rsp * 4;                  // NC=4, BM=64 (layer 0)
  int rs128 = (N + 127) / 128;         // 157 row strips (BM=128)
  int rsp128 = ((rs128 + 7) / 8) * 8;  // 160
  int blk1 = rsp128 * 4;               // NC=4, BM=128 (layer 1)
  int blk2 = rsp;                      // NC=1, BM=64 (layer 2)

  // layer 0: fp32 x -> xlb (fp8) + stats
  gemm_f32a_kernel<4><<<blk0, 256, 0, stream>>>(x, w0h, w0l, xlb, as0, ad0,
                                                asn, adn, N, 128);
  agg4_kernel<<<nwb4, 256, 0, stream>>>(xlb, asn, adn, offs, srcs, b0, hb, N);

  // layer 1: bf16 h0 -> xlb (fp8) + stats (BM=128 tile)
  gemm_bf16a128_kernel<4><<<blk1, 256, 0, stream>>>(hb, w1h, w1l, xlb, as1, ad1,
                                                    asn, adn, N, 512);
  agg4_kernel<<<nwb4, 256, 0, stream>>>(xlb, asn, adn, offs, srcs, b1, hb, N);

  // layer 2: bf16 h1 -> xlb (fp8, N*128) + stats; agg1+pool fused -> gp
  gemm_bf16a_kernel<1><<<blk2, 256, 0, stream>>>(hb, w2h, w2l, xlb, as2, ad2,
                                                 asn, adn, N, 512);
  agg1_pool_kernel<<<nwb4, 256, 0, stream>>>(xlb, asn, adn, offs, srcs, b2, gp, N);

  // MLP (folds the 64 shards)
  mlp_kernel<<<1, 128, 0, stream>>>(gp, Wm1, bm1, Wm2, bm2, (float*)d_out,
                                    1.0f / (float)N);
}